// Round 5
// baseline (177.292 us; speedup 1.0000x reference)
//
#include <hip/hip_runtime.h>
#include <hip/hip_bf16.h>

using short8 = __attribute__((ext_vector_type(8))) short;
using f32x4  = __attribute__((ext_vector_type(4))) float;
using f32x16 = __attribute__((ext_vector_type(16))) float;
using uint2v = __attribute__((ext_vector_type(2))) unsigned;

#define B_  4
#define KD  128      // head dim / model dim k
#define T_  2048
#define H_  8
#define HK  (H_*KD)  // 1024
#define NT  (T_/64)  // 32 KV tiles

__device__ __forceinline__ ushort f2bf(float f) {
    unsigned u = __builtin_bit_cast(unsigned, f);
    u += 0x7fffu + ((u >> 16) & 1u);
    return (ushort)(u >> 16);
}

__device__ __forceinline__ unsigned cvt_pk_bf16(float lo, float hi) {
    unsigned r;
    asm("v_cvt_pk_bf16_f32 %0, %1, %2" : "=v"(r) : "v"(lo), "v"(hi));
    return r;
}

// x: [B][KD][T_] f32 -> xt: [B][T_][KD] bf16 via LDS tile transpose (both sides coalesced)
__global__ __launch_bounds__(256) void cvt_x_kernel(const float* __restrict__ x,
                                                    ushort* __restrict__ xt) {
    __shared__ float tile[64][65];
    int t0 = (blockIdx.x & 31) * 64;
    int k0 = ((blockIdx.x >> 5) & 1) * 64;
    int b  = blockIdx.x >> 6;
    int c  = threadIdx.x & 63;
    int r4 = threadIdx.x >> 6;          // 0..3
    #pragma unroll
    for (int i = 0; i < 16; i++) {
        int k = r4 * 16 + i;
        tile[k][c] = x[((size_t)b * KD + k0 + k) * T_ + t0 + c];
    }
    __syncthreads();
    #pragma unroll
    for (int i = 0; i < 16; i++) {
        int t = r4 * 16 + i;
        xt[((size_t)b * T_ + t0 + t) * KD + k0 + c] = f2bf(tile[c][t]);
    }
}

__global__ __launch_bounds__(256) void cvt_w_kernel(const float* __restrict__ w,
                                                    ushort* __restrict__ o, int n) {
    int i = blockIdx.x * 256 + threadIdx.x;
    if (i < n) o[i] = f2bf(w[i]);
}

// C[m][n] = scale * sum_k A[m][k] * B[n][k]; bf16 in/out
__global__ __launch_bounds__(256) void gemm_abT(const ushort* __restrict__ A, long sA,
                                                const ushort* __restrict__ B, long sB,
                                                ushort* __restrict__ C, long sC,
                                                int M, int N, int Kd, float scale) {
    int b = blockIdx.z;
    A += (long)b * sA;  B += (long)b * sB;  C += (long)b * sC;
    int lane = threadIdx.x & 63;
    int w    = threadIdx.x >> 6;
    int lr = lane & 15, lg = lane >> 4;
    int m0 = blockIdx.x * 64 + (w >> 1) * 32;
    int n0 = blockIdx.y * 64 + (w & 1) * 32;

    f32x4 acc[2][2] = {};
    for (int k0 = 0; k0 < Kd; k0 += 32) {
        short8 af[2], bf[2];
        #pragma unroll
        for (int i = 0; i < 2; i++)
            af[i] = *(const short8*)(A + (long)(m0 + i*16 + lr) * Kd + k0 + lg*8);
        #pragma unroll
        for (int j = 0; j < 2; j++)
            bf[j] = *(const short8*)(B + (long)(n0 + j*16 + lr) * Kd + k0 + lg*8);
        #pragma unroll
        for (int i = 0; i < 2; i++)
            #pragma unroll
            for (int j = 0; j < 2; j++)
                acc[i][j] = __builtin_amdgcn_mfma_f32_16x16x32_bf16(af[i], bf[j], acc[i][j], 0, 0, 0);
    }
    #pragma unroll
    for (int i = 0; i < 2; i++)
        #pragma unroll
        for (int j = 0; j < 2; j++)
            #pragma unroll
            for (int r = 0; r < 4; r++) {
                int m = m0 + i*16 + lg*4 + r;
                int n = n0 + j*16 + lr;
                C[(long)m * N + n] = f2bf(acc[i][j][r] * scale);
            }
}

// out[m][n] = sum_k A[m][k]*B[n][k] + bias[m];  f32 out
__global__ __launch_bounds__(256) void gemm_abT_f32bias(const ushort* __restrict__ A,
                                                        const ushort* __restrict__ B, long sB,
                                                        const float* __restrict__ bias,
                                                        float* __restrict__ C, long sC,
                                                        int M, int N, int Kd) {
    int b = blockIdx.z;
    B += (long)b * sB;  C += (long)b * sC;
    int lane = threadIdx.x & 63;
    int w    = threadIdx.x >> 6;
    int lr = lane & 15, lg = lane >> 4;
    int m0 = blockIdx.x * 64 + (w >> 1) * 32;
    int n0 = blockIdx.y * 64 + (w & 1) * 32;

    f32x4 acc[2][2] = {};
    for (int k0 = 0; k0 < Kd; k0 += 32) {
        short8 af[2], bf[2];
        #pragma unroll
        for (int i = 0; i < 2; i++)
            af[i] = *(const short8*)(A + (long)(m0 + i*16 + lr) * Kd + k0 + lg*8);
        #pragma unroll
        for (int j = 0; j < 2; j++)
            bf[j] = *(const short8*)(B + (long)(n0 + j*16 + lr) * Kd + k0 + lg*8);
        #pragma unroll
        for (int i = 0; i < 2; i++)
            #pragma unroll
            for (int j = 0; j < 2; j++)
                acc[i][j] = __builtin_amdgcn_mfma_f32_16x16x32_bf16(af[i], bf[j], acc[i][j], 0, 0, 0);
    }
    #pragma unroll
    for (int i = 0; i < 2; i++)
        #pragma unroll
        for (int j = 0; j < 2; j++)
            #pragma unroll
            for (int r = 0; r < 4; r++) {
                int m = m0 + i*16 + lg*4 + r;
                int n = n0 + j*16 + lr;
                C[(long)m * N + n] = acc[i][j][r] + bias[m];
            }
}

// online-softmax + P-pack for one 32-query block (verified r3/r4 code path)
__device__ __forceinline__ void softmax_pack(f32x16 &s0, f32x16 &s1,
                                             float &m_q, float &l_q,
                                             f32x16 *o_acc, short8 *ap, int hi) {
    float mx[8];
    #pragma unroll
    for (int i = 0; i < 8; i++)
        mx[i] = fmaxf(fmaxf(s0[i], s0[i+8]), fmaxf(s1[i], s1[i+8]));
    #pragma unroll
    for (int st = 4; st > 0; st >>= 1)
        #pragma unroll
        for (int i = 0; i < st; i++) mx[i] = fmaxf(mx[i], mx[i+st]);
    float pmax = fmaxf(mx[0], __shfl_xor(mx[0], 32));

    if (!__all(pmax - m_q <= 8.f)) {            // defer-max (T13)
        float mnew = fmaxf(m_q, pmax);
        float corr = __expf(m_q - mnew);
        l_q *= corr;
        m_q = mnew;
        #pragma unroll
        for (int r = 0; r < 16; r++) {
            float cr = __shfl(corr, (r & 3) + 8 * (r >> 2) + 4 * hi);
            #pragma unroll
            for (int dn = 0; dn < 4; dn++) o_acc[dn][r] *= cr;
        }
    }

    float ls0 = 0.f, ls1 = 0.f, ls2 = 0.f, ls3 = 0.f;
    #pragma unroll
    for (int r = 0; r < 16; r++) {
        float e0 = __expf(s0[r] - m_q);
        float e1 = __expf(s1[r] - m_q);
        s0[r] = e0; s1[r] = e1;
        if (r & 1) { ls1 += e0; ls3 += e1; } else { ls0 += e0; ls2 += e1; }
    }
    float lsum = (ls0 + ls1) + (ls2 + ls3);
    lsum += __shfl_xor(lsum, 32);
    l_q += lsum;

    unsigned uu[2][4][2];
    #pragma unroll
    for (int m4 = 0; m4 < 4; m4++) {
        uu[0][m4][0] = cvt_pk_bf16(s0[4*m4+0], s0[4*m4+1]);
        uu[0][m4][1] = cvt_pk_bf16(s0[4*m4+2], s0[4*m4+3]);
        uu[1][m4][0] = cvt_pk_bf16(s1[4*m4+0], s1[4*m4+1]);
        uu[1][m4][1] = cvt_pk_bf16(s1[4*m4+2], s1[4*m4+3]);
    }
    #pragma unroll
    for (int ks = 0; ks < 4; ks++) {
        int nt = ks >> 1, j = ks & 1;
        unsigned lo0 = uu[nt][2*j][0],   lo1 = uu[nt][2*j][1];
        unsigned hi0 = uu[nt][2*j+1][0], hi1 = uu[nt][2*j+1][1];
        uint2v r0 = __builtin_amdgcn_permlane32_swap(lo0, hi0, false, false);
        uint2v r1 = __builtin_amdgcn_permlane32_swap(lo1, hi1, false, false);
        union { unsigned wd[4]; short8 v; } c;
        c.wd[0] = r0[0];
        c.wd[1] = r1[0];
        c.wd[2] = r0[1];
        c.wd[3] = r1[1];
        ap[ks] = c.v;
    }
}

// Flash attention: 4 waves x 64 queries (2x 32-q blocks per wave) so each
// K/V LDS fragment read feeds 2 MFMAs (halves LDS read traffic vs r4).
// K/V double-buffered in XOR-swizzled LDS, reg-staged async (T14).
__global__ __launch_bounds__(256, 1) void attn32_kernel(const ushort* __restrict__ qt,
                                                        const ushort* __restrict__ kt,
                                                        const ushort* __restrict__ vs,
                                                        ushort* __restrict__ ot) {
    int f = blockIdx.x;
    int xcd = f & 7, u = f >> 3;
    int qt8 = u & 7, gh = u >> 3;
    int g = xcd + 8 * gh;                  // 0..31 == h + 8*b
    int h = g & 7, b = g >> 3;
    int w    = threadIdx.x >> 6;           // 0..3
    int lane = threadIdx.x & 63;
    int lq = lane & 31, hi = lane >> 5;
    int hi8 = hi * 8;
    int q0A = qt8 * 256 + w * 64;
    int q0B = q0A + 32;

    __shared__ __align__(16) ushort k_lds[2][64 * 128];
    __shared__ __align__(16) ushort v_lds[2][128 * 64];

    // staging: 256 threads, K row kr cols [kc0,kc0+32), V row vr cols [vc0,vc0+32)
    int tid = threadIdx.x;
    int kr = tid >> 2, kc0 = (tid & 3) << 5;
    int vr = tid >> 1, vc0 = (tid & 1) << 5;
    const ushort* kst = kt + ((size_t)b * T_ + kr) * HK + h * KD + kc0;
    const ushort* vst = vs + ((size_t)b * HK + h * KD + vr) * T_ + vc0;
    int ksw = (kr & 7) << 3, vsw = (vr & 7) << 3;
    int kwi[4], vwi[4];
    #pragma unroll
    for (int j = 0; j < 4; j++) {
        kwi[j] = kr * 128 + ((kc0 + j*8) ^ ksw);
        vwi[j] = vr * 64  + ((vc0 + j*8) ^ vsw);
    }

    // Q fragments for both blocks
    const ushort* qbA = qt + ((size_t)b * T_ + q0A + lq) * HK + h * KD + hi8;
    const ushort* qbB = qt + ((size_t)b * T_ + q0B + lq) * HK + h * KD + hi8;
    short8 qfA[8], qfB[8];
    #pragma unroll
    for (int dc = 0; dc < 8; dc++) {
        qfA[dc] = *(const short8*)(qbA + dc * 16);
        qfB[dc] = *(const short8*)(qbB + dc * 16);
    }

    // prologue: stage tile 0, issue loads for tile 1
    short8 rk[4], rv[4];
    #pragma unroll
    for (int j = 0; j < 4; j++) {
        rk[j] = *(const short8*)(kst + j*8);
        rv[j] = *(const short8*)(vst + j*8);
    }
    #pragma unroll
    for (int j = 0; j < 4; j++) {
        *(short8*)&k_lds[0][kwi[j]] = rk[j];
        *(short8*)&v_lds[0][vwi[j]] = rv[j];
    }
    #pragma unroll
    for (int j = 0; j < 4; j++) {
        rk[j] = *(const short8*)(kst + (size_t)64 * HK + j*8);
        rv[j] = *(const short8*)(vst + 64 + j*8);
    }
    __syncthreads();

    f32x16 o_accA[4] = {}, o_accB[4] = {};
    float m_qA = -1e30f, l_qA = 0.f, m_qB = -1e30f, l_qB = 0.f;
    const int xsw = (lq & 7) << 3;

    for (int t = 0; t < NT; ++t) {
        const int cur = t & 1;
        // ---- QK^T: each kf read feeds both q-blocks ----
        f32x16 sA0 = {}, sA1 = {}, sB0 = {}, sB1 = {};
        const ushort* kr0 = &k_lds[cur][(size_t)lq * 128];
        const ushort* kr1 = &k_lds[cur][(size_t)(32 + lq) * 128];
        #pragma unroll
        for (int dc = 0; dc < 8; dc++) {
            int c = (dc * 16 + hi8) ^ xsw;
            short8 kf0 = *(const short8*)(kr0 + c);
            short8 kf1 = *(const short8*)(kr1 + c);
            sA0 = __builtin_amdgcn_mfma_f32_32x32x16_bf16(kf0, qfA[dc], sA0, 0, 0, 0);
            sA1 = __builtin_amdgcn_mfma_f32_32x32x16_bf16(kf1, qfA[dc], sA1, 0, 0, 0);
            sB0 = __builtin_amdgcn_mfma_f32_32x32x16_bf16(kf0, qfB[dc], sB0, 0, 0, 0);
            sB1 = __builtin_amdgcn_mfma_f32_32x32x16_bf16(kf1, qfB[dc], sB1, 0, 0, 0);
        }

        short8 apA[4], apB[4];
        softmax_pack(sA0, sA1, m_qA, l_qA, o_accA, apA, hi);
        softmax_pack(sB0, sB1, m_qB, l_qB, o_accB, apB, hi);

        // ---- O += P V: each vf read feeds both blocks ----
        #pragma unroll
        for (int dn = 0; dn < 4; dn++) {
            const ushort* vrp = &v_lds[cur][(size_t)(dn*32 + lq) * 64];
            #pragma unroll
            for (int ks = 0; ks < 4; ks++) {
                int c = (ks * 16 + hi8) ^ xsw;
                short8 vf = *(const short8*)(vrp + c);
                o_accA[dn] = __builtin_amdgcn_mfma_f32_32x32x16_bf16(apA[ks], vf, o_accA[dn], 0, 0, 0);
                o_accB[dn] = __builtin_amdgcn_mfma_f32_32x32x16_bf16(apB[ks], vf, o_accB[dn], 0, 0, 0);
            }
        }

        __syncthreads();
        if (t + 1 < NT) {
            const int nxt = cur ^ 1;
            #pragma unroll
            for (int j = 0; j < 4; j++) {
                *(short8*)&k_lds[nxt][kwi[j]] = rk[j];
                *(short8*)&v_lds[nxt][vwi[j]] = rv[j];
            }
            if (t + 2 < NT) {
                size_t ko = (size_t)(t + 2) * 64 * HK;
                int    vo = (t + 2) * 64;
                #pragma unroll
                for (int j = 0; j < 4; j++) {
                    rk[j] = *(const short8*)(kst + ko + j*8);
                    rv[j] = *(const short8*)(vst + vo + j*8);
                }
            }
            __syncthreads();
        }
    }

    // epilogue
    float linvA = 1.f / l_qA, linvB = 1.f / l_qB;
    ushort* obA = ot + ((size_t)b * T_ + q0A) * HK + h * KD;
    ushort* obB = ot + ((size_t)b * T_ + q0B) * HK + h * KD;
    #pragma unroll
    for (int r = 0; r < 16; r++) {
        int qrow = (r & 3) + 8 * (r >> 2) + 4 * hi;
        float lA = __shfl(linvA, qrow);
        float lB = __shfl(linvB, qrow);
        #pragma unroll
        for (int dn = 0; dn < 4; dn++) {
            obA[(size_t)qrow * HK + dn*32 + lq] = f2bf(o_accA[dn][r] * lA);
            obB[(size_t)qrow * HK + dn*32 + lq] = f2bf(o_accB[dn][r] * lB);
        }
    }
}

extern "C" void kernel_launch(void* const* d_in, const int* in_sizes, int n_in,
                              void* d_out, int out_size, void* d_ws, size_t ws_size,
                              hipStream_t stream) {
    const float* x  = (const float*)d_in[0];
    const float* Wq = (const float*)d_in[1];
    const float* Wk = (const float*)d_in[2];
    const float* Wv = (const float*)d_in[3];
    const float* Wu = (const float*)d_in[4];
    const float* bu = (const float*)d_in[5];
    float* out = (float*)d_out;

    const size_t XT  = (size_t)B_ * T_ * KD * 2;
    const size_t WB  = (size_t)HK * KD * 2;
    const size_t BIG = (size_t)B_ * T_ * HK * 2;
    size_t need = XT + 4*WB + 4*BIG;
    if (ws_size < need) return;

    char* p = (char*)d_ws;
    ushort* xt  = (ushort*)p;            p += XT;
    ushort* wqb = (ushort*)p;            p += WB;
    ushort* wkb = (ushort*)p;            p += WB;
    ushort* wvb = (ushort*)p;            p += WB;
    ushort* wub = (ushort*)p;            p += WB;
    ushort* qtb = (ushort*)p;            p += BIG;
    ushort* ktb = (ushort*)p;            p += BIG;
    ushort* vsb = (ushort*)p;            p += BIG;
    ushort* otb = (ushort*)p;            p += BIG;

    cvt_x_kernel<<<256, 256, 0, stream>>>(x, xt);
    cvt_w_kernel<<<(HK*KD + 255)/256, 256, 0, stream>>>(Wq, wqb, HK*KD);
    cvt_w_kernel<<<(HK*KD + 255)/256, 256, 0, stream>>>(Wk, wkb, HK*KD);
    cvt_w_kernel<<<(HK*KD + 255)/256, 256, 0, stream>>>(Wv, wvb, HK*KD);
    cvt_w_kernel<<<(KD*HK + 255)/256, 256, 0, stream>>>(Wu, wub, KD*HK);

    const float qscale = 0.08838834764831845f;     // 1/sqrt(128)
    gemm_abT<<<dim3(T_/64, HK/64, B_), 256, 0, stream>>>(
        xt, (long)T_*KD, wqb, 0, qtb, (long)T_*HK, T_, HK, KD, qscale);
    gemm_abT<<<dim3(T_/64, HK/64, B_), 256, 0, stream>>>(
        xt, (long)T_*KD, wkb, 0, ktb, (long)T_*HK, T_, HK, KD, 1.f);
    gemm_abT<<<dim3(HK/64, T_/64, B_), 256, 0, stream>>>(
        wvb, 0, xt, (long)T_*KD, vsb, (long)HK*T_, HK, T_, KD, 1.f);

    attn32_kernel<<<dim3(256), 256, 0, stream>>>(qtb, ktb, vsb, otb);

    gemm_abT_f32bias<<<dim3(KD/64, T_/64, B_), 256, 0, stream>>>(
        wub, otb, (long)T_*HK, bu, out, (long)KD*T_, KD, T_, HK);
}

// Round 6
// 139.329 us; speedup vs baseline: 1.2725x; 1.2725x over previous
//
#include <hip/hip_runtime.h>
#include <hip/hip_bf16.h>

using short8 = __attribute__((ext_vector_type(8))) short;
using f32x4  = __attribute__((ext_vector_type(4))) float;
using f32x16 = __attribute__((ext_vector_type(16))) float;
using uint2v = __attribute__((ext_vector_type(2))) unsigned;

#define B_  4
#define KD  128      // head dim / model dim k
#define T_  2048
#define H_  8
#define HK  (H_*KD)  // 1024
#define NT  (T_/64)  // 32 KV tiles

__device__ __forceinline__ ushort f2bf(float f) {
    unsigned u = __builtin_bit_cast(unsigned, f);
    u += 0x7fffu + ((u >> 16) & 1u);
    return (ushort)(u >> 16);
}

__device__ __forceinline__ unsigned cvt_pk_bf16(float lo, float hi) {
    unsigned r;
    asm("v_cvt_pk_bf16_f32 %0, %1, %2" : "=v"(r) : "v"(lo), "v"(hi));
    return r;
}

// x: [B][KD][T_] f32 -> xt: [B][T_][KD] bf16 via LDS tile transpose (both sides coalesced)
__global__ __launch_bounds__(256) void cvt_x_kernel(const float* __restrict__ x,
                                                    ushort* __restrict__ xt) {
    __shared__ float tile[64][65];
    int t0 = (blockIdx.x & 31) * 64;
    int k0 = ((blockIdx.x >> 5) & 1) * 64;
    int b  = blockIdx.x >> 6;
    int c  = threadIdx.x & 63;
    int r4 = threadIdx.x >> 6;          // 0..3
    #pragma unroll
    for (int i = 0; i < 16; i++) {
        int k = r4 * 16 + i;
        tile[k][c] = x[((size_t)b * KD + k0 + k) * T_ + t0 + c];
    }
    __syncthreads();
    #pragma unroll
    for (int i = 0; i < 16; i++) {
        int t = r4 * 16 + i;
        xt[((size_t)b * T_ + t0 + t) * KD + k0 + c] = f2bf(tile[c][t]);
    }
}

// all four weight matrices -> bf16, outputs contiguous at dst (wq|wk|wv|wu)
__global__ __launch_bounds__(256) void cvt_w4_kernel(const float* __restrict__ Wq,
                                                     const float* __restrict__ Wk,
                                                     const float* __restrict__ Wv,
                                                     const float* __restrict__ Wu,
                                                     ushort* __restrict__ dst) {
    int i = blockIdx.x * 256 + threadIdx.x;       // 0 .. 4*HK*KD-1
    const int n1 = HK * KD;                       // 131072 (pow2)
    const float* src = (i < n1) ? Wq : (i < 2*n1) ? Wk : (i < 3*n1) ? Wv : Wu;
    dst[i] = f2bf(src[i & (n1 - 1)]);
}

// C[m][n] = scale * sum_k A[m][k]*B[n][k]; Kd=128 fixed, 128x128 block tile,
// 4 waves, wave = 64x64 via 2x2 mfma_32x32x16, K fully unrolled.
__global__ __launch_bounds__(256, 2) void gemm128(const ushort* __restrict__ A, long sA,
                                                  const ushort* __restrict__ B, long sB,
                                                  ushort* __restrict__ C, long sC,
                                                  int N, float scale) {
    int b = blockIdx.z;
    A += (size_t)b * sA;  B += (size_t)b * sB;  C += (size_t)b * sC;
    int lane = threadIdx.x & 63;
    int w    = threadIdx.x >> 6;
    int lq = lane & 31, hi = lane >> 5, hi8 = hi * 8;
    int m0 = blockIdx.x * 128 + (w >> 1) * 64;
    int n0 = blockIdx.y * 128 + (w & 1) * 64;

    const ushort* a0p = A + (size_t)(m0 + lq) * KD + hi8;
    const ushort* a1p = A + (size_t)(m0 + 32 + lq) * KD + hi8;
    const ushort* b0p = B + (size_t)(n0 + lq) * KD + hi8;
    const ushort* b1p = B + (size_t)(n0 + 32 + lq) * KD + hi8;

    f32x16 acc[2][2] = {};
    #pragma unroll
    for (int kc = 0; kc < 8; kc++) {
        short8 a0 = *(const short8*)(a0p + kc * 16);
        short8 a1 = *(const short8*)(a1p + kc * 16);
        short8 b0 = *(const short8*)(b0p + kc * 16);
        short8 b1 = *(const short8*)(b1p + kc * 16);
        acc[0][0] = __builtin_amdgcn_mfma_f32_32x32x16_bf16(a0, b0, acc[0][0], 0, 0, 0);
        acc[0][1] = __builtin_amdgcn_mfma_f32_32x32x16_bf16(a0, b1, acc[0][1], 0, 0, 0);
        acc[1][0] = __builtin_amdgcn_mfma_f32_32x32x16_bf16(a1, b0, acc[1][0], 0, 0, 0);
        acc[1][1] = __builtin_amdgcn_mfma_f32_32x32x16_bf16(a1, b1, acc[1][1], 0, 0, 0);
    }
    // D: col = n = lane&31 (B's row), row = m = (r&3)+8*(r>>2)+4*hi (A's row)
    #pragma unroll
    for (int i = 0; i < 2; i++)
        #pragma unroll
        for (int j = 0; j < 2; j++)
            #pragma unroll
            for (int r = 0; r < 16; r++) {
                int m = m0 + i*32 + (r & 3) + 8 * (r >> 2) + 4 * hi;
                int n = n0 + j*32 + lq;
                C[(size_t)m * N + n] = f2bf(acc[i][j][r] * scale);
            }
}

// out[m][n] = sum_k A[m][k]*B[n][k] + bias[m];  f32 out
__global__ __launch_bounds__(256) void gemm_abT_f32bias(const ushort* __restrict__ A,
                                                        const ushort* __restrict__ B, long sB,
                                                        const float* __restrict__ bias,
                                                        float* __restrict__ C, long sC,
                                                        int M, int N, int Kd) {
    int b = blockIdx.z;
    B += (long)b * sB;  C += (long)b * sC;
    int lane = threadIdx.x & 63;
    int w    = threadIdx.x >> 6;
    int lr = lane & 15, lg = lane >> 4;
    int m0 = blockIdx.x * 64 + (w >> 1) * 32;
    int n0 = blockIdx.y * 64 + (w & 1) * 32;

    f32x4 acc[2][2] = {};
    #pragma unroll 4
    for (int k0 = 0; k0 < Kd; k0 += 32) {
        short8 af[2], bf[2];
        #pragma unroll
        for (int i = 0; i < 2; i++)
            af[i] = *(const short8*)(A + (long)(m0 + i*16 + lr) * Kd + k0 + lg*8);
        #pragma unroll
        for (int j = 0; j < 2; j++)
            bf[j] = *(const short8*)(B + (long)(n0 + j*16 + lr) * Kd + k0 + lg*8);
        #pragma unroll
        for (int i = 0; i < 2; i++)
            #pragma unroll
            for (int j = 0; j < 2; j++)
                acc[i][j] = __builtin_amdgcn_mfma_f32_16x16x32_bf16(af[i], bf[j], acc[i][j], 0, 0, 0);
    }
    #pragma unroll
    for (int i = 0; i < 2; i++)
        #pragma unroll
        for (int j = 0; j < 2; j++)
            #pragma unroll
            for (int r = 0; r < 4; r++) {
                int m = m0 + i*16 + lg*4 + r;
                int n = n0 + j*16 + lr;
                C[(long)m * N + n] = acc[i][j][r] + bias[m];
            }
}

// Flash attention (r4-verified): 8 waves x 32 queries, 32x32x16 MFMA, swapped
// QK^T, in-register softmax. K/V double-buffered in XOR-swizzled LDS,
// reg-staged async (T14). qt pre-scaled by 1/sqrt(KD).
__global__ __launch_bounds__(512, 2) void attn32_kernel(const ushort* __restrict__ qt,
                                                        const ushort* __restrict__ kt,
                                                        const ushort* __restrict__ vs,
                                                        ushort* __restrict__ ot) {
    int f = blockIdx.x;
    int xcd = f & 7, u = f >> 3;
    int qt8 = u & 7, gh = u >> 3;
    int g = xcd + 8 * gh;                  // 0..31 == h + 8*b
    int h = g & 7, b = g >> 3;
    int w    = threadIdx.x >> 6;
    int lane = threadIdx.x & 63;
    int lq = lane & 31, hi = lane >> 5;
    int hi8 = hi * 8;
    int q0w = qt8 * 256 + w * 32;

    __shared__ __align__(16) ushort k_lds[2][64 * 128];
    __shared__ __align__(16) ushort v_lds[2][128 * 64];

    int tid  = threadIdx.x;
    int krow = tid >> 3, kcol = (tid & 7) << 4;
    const ushort* kst = kt + ((size_t)b * T_ + krow) * HK + h * KD + kcol;
    int kwi = krow * 128 + (kcol ^ ((krow & 7) << 3));
    int vrow = tid >> 2, vcol = (tid & 3) << 4;
    const ushort* vst = vs + ((size_t)b * HK + h * KD + vrow) * T_ + vcol;
    int vwi = vrow * 64 + (vcol ^ ((vrow & 7) << 3));

    const ushort* qbase = qt + ((size_t)b * T_ + q0w + lq) * HK + h * KD + hi8;

    short8 qf[8];
    #pragma unroll
    for (int dc = 0; dc < 8; dc++)
        qf[dc] = *(const short8*)(qbase + dc * 16);

    short8 rk0 = *(const short8*)(kst);
    short8 rk1 = *(const short8*)(kst + 8);
    short8 rv0 = *(const short8*)(vst);
    short8 rv1 = *(const short8*)(vst + 8);
    *(short8*)&k_lds[0][kwi]     = rk0;
    *(short8*)&k_lds[0][kwi ^ 8] = rk1;
    *(short8*)&v_lds[0][vwi]     = rv0;
    *(short8*)&v_lds[0][vwi ^ 8] = rv1;
    rk0 = *(const short8*)(kst + (size_t)64 * HK);
    rk1 = *(const short8*)(kst + (size_t)64 * HK + 8);
    rv0 = *(const short8*)(vst + 64);
    rv1 = *(const short8*)(vst + 64 + 8);
    __syncthreads();

    f32x16 o_acc[4] = {};
    float m_q = -1e30f, l_q = 0.f;
    const int xsw = (lq & 7) << 3;

    for (int t = 0; t < NT; ++t) {
        const int cur = t & 1;
        f32x16 s0 = {}, s1 = {};
        const ushort* kr0 = &k_lds[cur][(size_t)lq * 128];
        const ushort* kr1 = &k_lds[cur][(size_t)(32 + lq) * 128];
        #pragma unroll
        for (int dc = 0; dc < 8; dc++) {
            int c = (dc * 16 + hi8) ^ xsw;
            short8 kf0 = *(const short8*)(kr0 + c);
            short8 kf1 = *(const short8*)(kr1 + c);
            s0 = __builtin_amdgcn_mfma_f32_32x32x16_bf16(kf0, qf[dc], s0, 0, 0, 0);
            s1 = __builtin_amdgcn_mfma_f32_32x32x16_bf16(kf1, qf[dc], s1, 0, 0, 0);
        }

        float mx[8];
        #pragma unroll
        for (int i = 0; i < 8; i++)
            mx[i] = fmaxf(fmaxf(s0[i], s0[i+8]), fmaxf(s1[i], s1[i+8]));
        #pragma unroll
        for (int st = 4; st > 0; st >>= 1)
            #pragma unroll
            for (int i = 0; i < st; i++) mx[i] = fmaxf(mx[i], mx[i+st]);
        float pmax = fmaxf(mx[0], __shfl_xor(mx[0], 32));

        if (!__all(pmax - m_q <= 8.f)) {
            float mnew = fmaxf(m_q, pmax);
            float corr = __expf(m_q - mnew);
            l_q *= corr;
            m_q = mnew;
            #pragma unroll
            for (int r = 0; r < 16; r++) {
                float cr = __shfl(corr, (r & 3) + 8 * (r >> 2) + 4 * hi);
                #pragma unroll
                for (int dn = 0; dn < 4; dn++) o_acc[dn][r] *= cr;
            }
        }

        float ls0 = 0.f, ls1 = 0.f, ls2 = 0.f, ls3 = 0.f;
        #pragma unroll
        for (int r = 0; r < 16; r++) {
            float e0 = __expf(s0[r] - m_q);
            float e1 = __expf(s1[r] - m_q);
            s0[r] = e0; s1[r] = e1;
            if (r & 1) { ls1 += e0; ls3 += e1; } else { ls0 += e0; ls2 += e1; }
        }
        float lsum = (ls0 + ls1) + (ls2 + ls3);
        lsum += __shfl_xor(lsum, 32);
        l_q += lsum;

        unsigned uu[2][4][2];
        #pragma unroll
        for (int m4 = 0; m4 < 4; m4++) {
            uu[0][m4][0] = cvt_pk_bf16(s0[4*m4+0], s0[4*m4+1]);
            uu[0][m4][1] = cvt_pk_bf16(s0[4*m4+2], s0[4*m4+3]);
            uu[1][m4][0] = cvt_pk_bf16(s1[4*m4+0], s1[4*m4+1]);
            uu[1][m4][1] = cvt_pk_bf16(s1[4*m4+2], s1[4*m4+3]);
        }
        short8 ap[4];
        #pragma unroll
        for (int ks = 0; ks < 4; ks++) {
            int nt = ks >> 1, j = ks & 1;
            unsigned lo0 = uu[nt][2*j][0],   lo1 = uu[nt][2*j][1];
            unsigned hi0 = uu[nt][2*j+1][0], hi1 = uu[nt][2*j+1][1];
            uint2v r0 = __builtin_amdgcn_permlane32_swap(lo0, hi0, false, false);
            uint2v r1 = __builtin_amdgcn_permlane32_swap(lo1, hi1, false, false);
            union { unsigned wd[4]; short8 v; } c;
            c.wd[0] = r0[0];
            c.wd[1] = r1[0];
            c.wd[2] = r0[1];
            c.wd[3] = r1[1];
            ap[ks] = c.v;
        }

        #pragma unroll
        for (int dn = 0; dn < 4; dn++) {
            const ushort* vr = &v_lds[cur][(size_t)(dn*32 + lq) * 64];
            #pragma unroll
            for (int ks = 0; ks < 4; ks++) {
                int c = (ks * 16 + hi8) ^ xsw;
                short8 vf = *(const short8*)(vr + c);
                o_acc[dn] = __builtin_amdgcn_mfma_f32_32x32x16_bf16(ap[ks], vf, o_acc[dn], 0, 0, 0);
            }
        }

        __syncthreads();
        if (t + 1 < NT) {
            const int nxt = cur ^ 1;
            *(short8*)&k_lds[nxt][kwi]     = rk0;
            *(short8*)&k_lds[nxt][kwi ^ 8] = rk1;
            *(short8*)&v_lds[nxt][vwi]     = rv0;
            *(short8*)&v_lds[nxt][vwi ^ 8] = rv1;
            if (t + 2 < NT) {
                size_t ko = (size_t)(t + 2) * 64 * HK;
                int    vo = (t + 2) * 64;
                rk0 = *(const short8*)(kst + ko);
                rk1 = *(const short8*)(kst + ko + 8);
                rv0 = *(const short8*)(vst + vo);
                rv1 = *(const short8*)(vst + vo + 8);
            }
            __syncthreads();
        }
    }

    float linv = 1.f / l_q;
    ushort* ob = ot + ((size_t)b * T_ + q0w) * HK + h * KD;
    #pragma unroll
    for (int r = 0; r < 16; r++) {
        int qrow = (r & 3) + 8 * (r >> 2) + 4 * hi;
        float lr_ = __shfl(linv, qrow);
        #pragma unroll
        for (int dn = 0; dn < 4; dn++)
            ob[(size_t)qrow * HK + dn*32 + lq] = f2bf(o_acc[dn][r] * lr_);
    }
}

extern "C" void kernel_launch(void* const* d_in, const int* in_sizes, int n_in,
                              void* d_out, int out_size, void* d_ws, size_t ws_size,
                              hipStream_t stream) {
    const float* x  = (const float*)d_in[0];
    const float* Wq = (const float*)d_in[1];
    const float* Wk = (const float*)d_in[2];
    const float* Wv = (const float*)d_in[3];
    const float* Wu = (const float*)d_in[4];
    const float* bu = (const float*)d_in[5];
    float* out = (float*)d_out;

    const size_t XT  = (size_t)B_ * T_ * KD * 2;
    const size_t WB  = (size_t)HK * KD * 2;
    const size_t BIG = (size_t)B_ * T_ * HK * 2;
    size_t need = XT + 4*WB + 4*BIG;
    if (ws_size < need) return;

    char* p = (char*)d_ws;
    ushort* xt  = (ushort*)p;            p += XT;
    ushort* wqb = (ushort*)p;            p += WB;   // wq|wk|wv|wu contiguous
    ushort* wkb = (ushort*)p;            p += WB;
    ushort* wvb = (ushort*)p;            p += WB;
    ushort* wub = (ushort*)p;            p += WB;
    ushort* qtb = (ushort*)p;            p += BIG;
    ushort* ktb = (ushort*)p;            p += BIG;
    ushort* vsb = (ushort*)p;            p += BIG;
    ushort* otb = (ushort*)p;            p += BIG;

    cvt_x_kernel<<<256, 256, 0, stream>>>(x, xt);
    cvt_w4_kernel<<<(4*HK*KD)/256, 256, 0, stream>>>(Wq, Wk, Wv, Wu, wqb);

    const float qscale = 0.08838834764831845f;     // 1/sqrt(128)
    // qt[b][t][j], kt[b][t][j]
    gemm128<<<dim3(T_/128, HK/128, B_), 256, 0, stream>>>(
        xt, (long)T_*KD, wqb, 0, qtb, (long)T_*HK, HK, qscale);
    gemm128<<<dim3(T_/128, HK/128, B_), 256, 0, stream>>>(
        xt, (long)T_*KD, wkb, 0, ktb, (long)T_*HK, HK, 1.f);
    // vs[b][j][t]
    gemm128<<<dim3(HK/128, T_/128, B_), 256, 0, stream>>>(
        wvb, 0, xt, (long)T_*KD, vsb, (long)HK*T_, T_, 1.f);

    attn32_kernel<<<dim3(256), 512, 0, stream>>>(qtb, ktb, vsb, otb);

    gemm_abT_f32bias<<<dim3(KD/64, T_/64, B_), 256, 0, stream>>>(
        wub, otb, (long)T_*HK, bu, out, (long)KD*T_, KD, T_, HK);
}

// Round 8
// 129.703 us; speedup vs baseline: 1.3669x; 1.0742x over previous
//
#include <hip/hip_runtime.h>
#include <hip/hip_bf16.h>

using short8 = __attribute__((ext_vector_type(8))) short;
using f32x4  = __attribute__((ext_vector_type(4))) float;
using f32x16 = __attribute__((ext_vector_type(16))) float;
using uint2v = __attribute__((ext_vector_type(2))) unsigned;

#define B_  4
#define KD  128      // head dim / model dim k
#define T_  2048
#define H_  8
#define HK  (H_*KD)  // 1024
#define NT  (T_/64)  // 32 KV tiles

__device__ __forceinline__ ushort f2bf(float f) {
    unsigned u = __builtin_bit_cast(unsigned, f);
    u += 0x7fffu + ((u >> 16) & 1u);
    return (ushort)(u >> 16);
}

__device__ __forceinline__ unsigned cvt_pk_bf16(float lo, float hi) {
    unsigned r;
    asm("v_cvt_pk_bf16_f32 %0, %1, %2" : "=v"(r) : "v"(lo), "v"(hi));
    return r;
}

// Fused prep: blocks [0,2048) convert the 4 weight mats (contiguous dst),
// blocks [2048,2304) transpose x [B][KD][T] f32 -> xt [B][T][KD] bf16.
__global__ __launch_bounds__(256) void prep_kernel(const float* __restrict__ x,
                                                   const float* __restrict__ Wq,
                                                   const float* __restrict__ Wk,
                                                   const float* __restrict__ Wv,
                                                   const float* __restrict__ Wu,
                                                   ushort* __restrict__ wdst,
                                                   ushort* __restrict__ xt) {
    __shared__ float tile[64][65];
    int bx = blockIdx.x;
    if (bx < 2048) {
        int i = bx * 256 + threadIdx.x;
        const int n1 = HK * KD;
        const float* src = (i < n1) ? Wq : (i < 2*n1) ? Wk : (i < 3*n1) ? Wv : Wu;
        wdst[i] = f2bf(src[i & (n1 - 1)]);
        return;
    }
    int bi = bx - 2048;
    int t0 = (bi & 31) * 64;
    int k0 = ((bi >> 5) & 1) * 64;
    int b  = bi >> 6;
    int c  = threadIdx.x & 63;
    int r4 = threadIdx.x >> 6;
    #pragma unroll
    for (int i = 0; i < 16; i++) {
        int k = r4 * 16 + i;
        tile[k][c] = x[((size_t)b * KD + k0 + k) * T_ + t0 + c];
    }
    __syncthreads();
    #pragma unroll
    for (int i = 0; i < 16; i++) {
        int t = r4 * 16 + i;
        xt[((size_t)b * T_ + t0 + t) * KD + k0 + c] = f2bf(tile[c][t]);
    }
}

// Fused projections: grid (128, 12). blockIdx.y: which = y>>2 (0=Q,1=K,2=V), b = y&3.
// which 0/1: C[t][j] = sum_k xt[t][k] W[j][k];  which 2: C[j][t] (V transposed).
// 128x128 block tile, wave 64x64 via 2x2 mfma_32x32x16; loads hoisted ahead
// of the MFMA burst (single latency exposure). Math identical to r6 gemm128.
__global__ __launch_bounds__(256, 2) void proj_kernel(const ushort* __restrict__ xt,
                                                      const ushort* __restrict__ wall,
                                                      ushort* __restrict__ qtb,
                                                      ushort* __restrict__ ktb,
                                                      ushort* __restrict__ vsb) {
    int bz = blockIdx.y;
    int which = bz >> 2, b = bz & 3;
    int tidb = blockIdx.x;                 // 0..127
    const ushort *A, *Bp;
    ushort* C;
    int N, m0, n0;
    float scale = 1.f;
    if (which < 2) {
        m0 = (tidb >> 3) * 128;            // t-tile (16)
        n0 = (tidb & 7) * 128;             // j-tile (8)
        A  = xt + (size_t)b * T_ * KD;
        Bp = wall + (size_t)which * (HK * KD);
        C  = (which ? ktb : qtb) + (size_t)b * T_ * HK;
        N  = HK;
        if (which == 0) scale = 0.08838834764831845f;   // 1/sqrt(128)
    } else {
        m0 = (tidb >> 4) * 128;            // j-tile (8)
        n0 = (tidb & 15) * 128;            // t-tile (16)
        A  = wall + (size_t)2 * (HK * KD);
        Bp = xt + (size_t)b * T_ * KD;
        C  = vsb + (size_t)b * HK * T_;
        N  = T_;
    }
    int lane = threadIdx.x & 63;
    int w    = threadIdx.x >> 6;
    int lq = lane & 31, hi = lane >> 5, hi8 = hi * 8;
    m0 += (w >> 1) * 64;
    n0 += (w & 1) * 64;

    const ushort* a0p = A  + (size_t)(m0 + lq) * KD + hi8;
    const ushort* a1p = A  + (size_t)(m0 + 32 + lq) * KD + hi8;
    const ushort* b0p = Bp + (size_t)(n0 + lq) * KD + hi8;
    const ushort* b1p = Bp + (size_t)(n0 + 32 + lq) * KD + hi8;

    short8 a0[8], a1[8], b0[8], b1[8];
    #pragma unroll
    for (int kc = 0; kc < 8; kc++) {
        a0[kc] = *(const short8*)(a0p + kc * 16);
        a1[kc] = *(const short8*)(a1p + kc * 16);
        b0[kc] = *(const short8*)(b0p + kc * 16);
        b1[kc] = *(const short8*)(b1p + kc * 16);
    }
    f32x16 acc[2][2] = {};
    #pragma unroll
    for (int kc = 0; kc < 8; kc++) {
        acc[0][0] = __builtin_amdgcn_mfma_f32_32x32x16_bf16(a0[kc], b0[kc], acc[0][0], 0, 0, 0);
        acc[0][1] = __builtin_amdgcn_mfma_f32_32x32x16_bf16(a0[kc], b1[kc], acc[0][1], 0, 0, 0);
        acc[1][0] = __builtin_amdgcn_mfma_f32_32x32x16_bf16(a1[kc], b0[kc], acc[1][0], 0, 0, 0);
        acc[1][1] = __builtin_amdgcn_mfma_f32_32x32x16_bf16(a1[kc], b1[kc], acc[1][1], 0, 0, 0);
    }
    #pragma unroll
    for (int i = 0; i < 2; i++)
        #pragma unroll
        for (int j = 0; j < 2; j++)
            #pragma unroll
            for (int r = 0; r < 16; r++) {
                int m = m0 + i*32 + (r & 3) + 8 * (r >> 2) + 4 * hi;
                int n = n0 + j*32 + lq;
                C[(size_t)m * N + n] = f2bf(acc[i][j][r] * scale);
            }
}

// out[m][n] = sum_k A[m][k]*B[n][k] + bias[m];  f32 out  (r6-verified version)
__global__ __launch_bounds__(256) void gemm_abT_f32bias(const ushort* __restrict__ A,
                                                        const ushort* __restrict__ B, long sB,
                                                        const float* __restrict__ bias,
                                                        float* __restrict__ C, long sC,
                                                        int M, int N, int Kd) {
    int b = blockIdx.z;
    B += (long)b * sB;  C += (long)b * sC;
    int lane = threadIdx.x & 63;
    int w    = threadIdx.x >> 6;
    int lr = lane & 15, lg = lane >> 4;
    int m0 = blockIdx.x * 64 + (w >> 1) * 32;
    int n0 = blockIdx.y * 64 + (w & 1) * 32;

    f32x4 acc[2][2] = {};
    #pragma unroll 4
    for (int k0 = 0; k0 < Kd; k0 += 32) {
        short8 af[2], bf[2];
        #pragma unroll
        for (int i = 0; i < 2; i++)
            af[i] = *(const short8*)(A + (long)(m0 + i*16 + lr) * Kd + k0 + lg*8);
        #pragma unroll
        for (int j = 0; j < 2; j++)
            bf[j] = *(const short8*)(B + (long)(n0 + j*16 + lr) * Kd + k0 + lg*8);
        #pragma unroll
        for (int i = 0; i < 2; i++)
            #pragma unroll
            for (int j = 0; j < 2; j++)
                acc[i][j] = __builtin_amdgcn_mfma_f32_16x16x32_bf16(af[i], bf[j], acc[i][j], 0, 0, 0);
    }
    #pragma unroll
    for (int i = 0; i < 2; i++)
        #pragma unroll
        for (int j = 0; j < 2; j++)
            #pragma unroll
            for (int r = 0; r < 4; r++) {
                int m = m0 + i*16 + lg*4 + r;
                int n = n0 + j*16 + lr;
                C[(long)m * N + n] = acc[i][j][r] + bias[m];
            }
}

// Flash attention (r4/r6-verified, UNCHANGED): 8 waves x 32 queries, grid 256.
__global__ __launch_bounds__(512, 2) void attn32_kernel(const ushort* __restrict__ qt,
                                                        const ushort* __restrict__ kt,
                                                        const ushort* __restrict__ vs,
                                                        ushort* __restrict__ ot) {
    int f = blockIdx.x;
    int xcd = f & 7, u = f >> 3;
    int qt8 = u & 7, gh = u >> 3;
    int g = xcd + 8 * gh;                  // 0..31 == h + 8*b
    int h = g & 7, b = g >> 3;
    int w    = threadIdx.x >> 6;
    int lane = threadIdx.x & 63;
    int lq = lane & 31, hi = lane >> 5;
    int hi8 = hi * 8;
    int q0w = qt8 * 256 + w * 32;

    __shared__ __align__(16) ushort k_lds[2][64 * 128];
    __shared__ __align__(16) ushort v_lds[2][128 * 64];

    int tid  = threadIdx.x;
    int krow = tid >> 3, kcol = (tid & 7) << 4;
    const ushort* kst = kt + ((size_t)b * T_ + krow) * HK + h * KD + kcol;
    int kwi = krow * 128 + (kcol ^ ((krow & 7) << 3));
    int vrow = tid >> 2, vcol = (tid & 3) << 4;
    const ushort* vst = vs + ((size_t)b * HK + h * KD + vrow) * T_ + vcol;
    int vwi = vrow * 64 + (vcol ^ ((vrow & 7) << 3));

    const ushort* qbase = qt + ((size_t)b * T_ + q0w + lq) * HK + h * KD + hi8;

    short8 qf[8];
    #pragma unroll
    for (int dc = 0; dc < 8; dc++)
        qf[dc] = *(const short8*)(qbase + dc * 16);

    short8 rk0 = *(const short8*)(kst);
    short8 rk1 = *(const short8*)(kst + 8);
    short8 rv0 = *(const short8*)(vst);
    short8 rv1 = *(const short8*)(vst + 8);
    *(short8*)&k_lds[0][kwi]     = rk0;
    *(short8*)&k_lds[0][kwi ^ 8] = rk1;
    *(short8*)&v_lds[0][vwi]     = rv0;
    *(short8*)&v_lds[0][vwi ^ 8] = rv1;
    rk0 = *(const short8*)(kst + (size_t)64 * HK);
    rk1 = *(const short8*)(kst + (size_t)64 * HK + 8);
    rv0 = *(const short8*)(vst + 64);
    rv1 = *(const short8*)(vst + 64 + 8);
    __syncthreads();

    f32x16 o_acc[4] = {};
    float m_q = -1e30f, l_q = 0.f;
    const int xsw = (lq & 7) << 3;

    for (int t = 0; t < NT; ++t) {
        const int cur = t & 1;
        f32x16 s0 = {}, s1 = {};
        const ushort* kr0 = &k_lds[cur][(size_t)lq * 128];
        const ushort* kr1 = &k_lds[cur][(size_t)(32 + lq) * 128];
        #pragma unroll
        for (int dc = 0; dc < 8; dc++) {
            int c = (dc * 16 + hi8) ^ xsw;
            short8 kf0 = *(const short8*)(kr0 + c);
            short8 kf1 = *(const short8*)(kr1 + c);
            s0 = __builtin_amdgcn_mfma_f32_32x32x16_bf16(kf0, qf[dc], s0, 0, 0, 0);
            s1 = __builtin_amdgcn_mfma_f32_32x32x16_bf16(kf1, qf[dc], s1, 0, 0, 0);
        }

        float mx[8];
        #pragma unroll
        for (int i = 0; i < 8; i++)
            mx[i] = fmaxf(fmaxf(s0[i], s0[i+8]), fmaxf(s1[i], s1[i+8]));
        #pragma unroll
        for (int st = 4; st > 0; st >>= 1)
            #pragma unroll
            for (int i = 0; i < st; i++) mx[i] = fmaxf(mx[i], mx[i+st]);
        float pmax = fmaxf(mx[0], __shfl_xor(mx[0], 32));

        if (!__all(pmax - m_q <= 8.f)) {
            float mnew = fmaxf(m_q, pmax);
            float corr = __expf(m_q - mnew);
            l_q *= corr;
            m_q = mnew;
            #pragma unroll
            for (int r = 0; r < 16; r++) {
                float cr = __shfl(corr, (r & 3) + 8 * (r >> 2) + 4 * hi);
                #pragma unroll
                for (int dn = 0; dn < 4; dn++) o_acc[dn][r] *= cr;
            }
        }

        float ls0 = 0.f, ls1 = 0.f, ls2 = 0.f, ls3 = 0.f;
        #pragma unroll
        for (int r = 0; r < 16; r++) {
            float e0 = __expf(s0[r] - m_q);
            float e1 = __expf(s1[r] - m_q);
            s0[r] = e0; s1[r] = e1;
            if (r & 1) { ls1 += e0; ls3 += e1; } else { ls0 += e0; ls2 += e1; }
        }
        float lsum = (ls0 + ls1) + (ls2 + ls3);
        lsum += __shfl_xor(lsum, 32);
        l_q += lsum;

        unsigned uu[2][4][2];
        #pragma unroll
        for (int m4 = 0; m4 < 4; m4++) {
            uu[0][m4][0] = cvt_pk_bf16(s0[4*m4+0], s0[4*m4+1]);
            uu[0][m4][1] = cvt_pk_bf16(s0[4*m4+2], s0[4*m4+3]);
            uu[1][m4][0] = cvt_pk_bf16(s1[4*m4+0], s1[4*m4+1]);
            uu[1][m4][1] = cvt_pk_bf16(s1[4*m4+2], s1[4*m4+3]);
        }
        short8 ap[4];
        #pragma unroll
        for (int ks = 0; ks < 4; ks++) {
            int nt = ks >> 1, j = ks & 1;
            unsigned lo0 = uu[nt][2*j][0],   lo1 = uu[nt][2*j][1];
            unsigned hi0 = uu[nt][2*j+1][0], hi1 = uu[nt][2*j+1][1];
            uint2v r0 = __builtin_amdgcn_permlane32_swap(lo0, hi0, false, false);
            uint2v r1 = __builtin_amdgcn_permlane32_swap(lo1, hi1, false, false);
            union { unsigned wd[4]; short8 v; } c;
            c.wd[0] = r0[0];
            c.wd[1] = r1[0];
            c.wd[2] = r0[1];
            c.wd[3] = r1[1];
            ap[ks] = c.v;
        }

        #pragma unroll
        for (int dn = 0; dn < 4; dn++) {
            const ushort* vr = &v_lds[cur][(size_t)(dn*32 + lq) * 64];
            #pragma unroll
            for (int ks = 0; ks < 4; ks++) {
                int c = (ks * 16 + hi8) ^ xsw;
                short8 vf = *(const short8*)(vr + c);
                o_acc[dn] = __builtin_amdgcn_mfma_f32_32x32x16_bf16(ap[ks], vf, o_acc[dn], 0, 0, 0);
            }
        }

        __syncthreads();
        if (t + 1 < NT) {
            const int nxt = cur ^ 1;
            *(short8*)&k_lds[nxt][kwi]     = rk0;
            *(short8*)&k_lds[nxt][kwi ^ 8] = rk1;
            *(short8*)&v_lds[nxt][vwi]     = rv0;
            *(short8*)&v_lds[nxt][vwi ^ 8] = rv1;
            if (t + 2 < NT) {
                size_t ko = (size_t)(t + 2) * 64 * HK;
                int    vo = (t + 2) * 64;
                rk0 = *(const short8*)(kst + ko);
                rk1 = *(const short8*)(kst + ko + 8);
                rv0 = *(const short8*)(vst + vo);
                rv1 = *(const short8*)(vst + vo + 8);
            }
            __syncthreads();
        }
    }

    float linv = 1.f / l_q;
    ushort* ob = ot + ((size_t)b * T_ + q0w) * HK + h * KD;
    #pragma unroll
    for (int r = 0; r < 16; r++) {
        int qrow = (r & 3) + 8 * (r >> 2) + 4 * hi;
        float lr_ = __shfl(linv, qrow);
        #pragma unroll
        for (int dn = 0; dn < 4; dn++)
            ob[(size_t)qrow * HK + dn*32 + lq] = f2bf(o_acc[dn][r] * lr_);
    }
}

extern "C" void kernel_launch(void* const* d_in, const int* in_sizes, int n_in,
                              void* d_out, int out_size, void* d_ws, size_t ws_size,
                              hipStream_t stream) {
    const float* x  = (const float*)d_in[0];
    const float* Wq = (const float*)d_in[1];
    const float* Wk = (const float*)d_in[2];
    const float* Wv = (const float*)d_in[3];
    const float* Wu = (const float*)d_in[4];
    const float* bu = (const float*)d_in[5];
    float* out = (float*)d_out;

    const size_t XT  = (size_t)B_ * T_ * KD * 2;
    const size_t WB  = (size_t)HK * KD * 2;
    const size_t BIG = (size_t)B_ * T_ * HK * 2;
    size_t need = XT + 4*WB + 4*BIG;
    if (ws_size < need) return;

    char* p = (char*)d_ws;
    ushort* xt  = (ushort*)p;            p += XT;
    ushort* wqb = (ushort*)p;            p += WB;   // wq|wk|wv|wu contiguous
    ushort* wkb = (ushort*)p;            p += WB;
    ushort* wvb = (ushort*)p;            p += WB;
    ushort* wub = (ushort*)p;            p += WB;
    ushort* qtb = (ushort*)p;            p += BIG;
    ushort* ktb = (ushort*)p;            p += BIG;
    ushort* vsb = (ushort*)p;            p += BIG;
    ushort* otb = (ushort*)p;            p += BIG;
    (void)wkb; (void)wvb;

    prep_kernel<<<2304, 256, 0, stream>>>(x, Wq, Wk, Wv, Wu, wqb, xt);

    proj_kernel<<<dim3(128, 12), 256, 0, stream>>>(xt, wqb, qtb, ktb, vsb);

    attn32_kernel<<<dim3(256), 512, 0, stream>>>(qtb, ktb, vsb, otb);

    gemm_abT_f32bias<<<dim3(KD/64, T_/64, B_), 256, 0, stream>>>(
        wub, otb, (long)T_*HK, bu, out, (long)KD*T_, KD, T_, HK);
}